// Round 5
// baseline (257.093 us; speedup 1.0000x reference)
//
#include <hip/hip_runtime.h>
#include <hip/hip_bf16.h>

#define N_ 256
#define D_ 64
#define H_ 4
#define DH_ 32
#define EQKV 384
#define NPOS 65536
#define SCALE_F 0.17677669529663687f
#define BIG_NEG -3.402823466e38f
#define H_STRIDE 72    // h tile stride (bf16)
#define Q_STRIDE 392   // K1 qkv staging stride (bf16); 784 B rows, 16B-aligned
#define PS 264         // fused: p_s stride (bf16)
#define OXS 136        // fused: O/x tile stride (bf16)
#define OFS 68         // fused: f32 out staging stride

typedef __attribute__((ext_vector_type(8))) short s16x8;
typedef __attribute__((ext_vector_type(4))) float f32x4;

// ws layout (bytes):
//   qkv     bf16 [65536][384]        @ 0          (50331648 B)
//   bias    f32  [4][i=256][j=256]   @ 50331648   (1048576 B)   [h][i][j], j fastest
//   h       bf16 [65536][64]         @ 51380224   (8388608 B)

__device__ inline short bfbits(float x) {
    __hip_bfloat16 b = __float2bfloat16(x);
    return *reinterpret_cast<short*>(&b);
}
__device__ inline float b2f(short s) {
    unsigned u = ((unsigned)(unsigned short)s) << 16;
    union { unsigned u; float f; } c; c.u = u; return c.f;
}
__device__ inline s16x8 cvt8(float4 a, float4 b) {
    s16x8 r;
    r[0] = bfbits(a.x); r[1] = bfbits(a.y); r[2] = bfbits(a.z); r[3] = bfbits(a.w);
    r[4] = bfbits(b.x); r[5] = bfbits(b.y); r[6] = bfbits(b.z); r[7] = bfbits(b.w);
    return r;
}

// ---------------- K1: layernorm + qkv + bias (MFMA), LDS-staged coalesced stores (unchanged) ----------------
__global__ __launch_bounds__(512) void k1_ln_proj_mfma(
    const float* __restrict__ z, const float* __restrict__ ln_w, const float* __restrict__ ln_b,
    const float* __restrict__ w_qkv, const float* __restrict__ w_bias,
    __hip_bfloat16* __restrict__ qkv_ws, __hip_bfloat16* __restrict__ h_ws,
    float* __restrict__ bias_ws)
{
    __shared__ __align__(16) short smem[64 * Q_STRIDE];
    const int t = threadIdx.x;
    const int wave = t >> 6, lane = t & 63;
    const int pos0 = blockIdx.x * 64;
    const int m = lane & 15, quad = lane >> 4;

    {
        const float lw = ln_w[lane], lb = ln_b[lane];
        const float wb0 = w_bias[lane], wb1 = w_bias[64 + lane],
                    wb2 = w_bias[128 + lane], wb3 = w_bias[192 + lane];
        for (int pp = 0; pp < 8; ++pp) {
            const int p = wave * 8 + pp;
            const float zv = z[(size_t)(pos0 + p) * 64 + lane];
            float s = zv, s2 = zv * zv;
            #pragma unroll
            for (int off = 32; off; off >>= 1) { s += __shfl_xor(s, off); s2 += __shfl_xor(s2, off); }
            const float mu = s * 0.015625f;
            const float var = s2 * 0.015625f - mu * mu;
            const float rs = rsqrtf(var + 1e-5f);
            const float hv = (zv - mu) * rs * lw + lb;
            smem[p * H_STRIDE + lane] = bfbits(hv);
            float b0 = hv * wb0, b1 = hv * wb1, b2 = hv * wb2, b3 = hv * wb3;
            #pragma unroll
            for (int off = 32; off; off >>= 1) {
                b0 += __shfl_xor(b0, off); b1 += __shfl_xor(b1, off);
                b2 += __shfl_xor(b2, off); b3 += __shfl_xor(b3, off);
            }
            if (lane < 4) {
                const int gpos = pos0 + p;
                const int gi = gpos >> 8, gj = gpos & 255;
                const float bv = lane == 0 ? b0 : lane == 1 ? b1 : lane == 2 ? b2 : b3;
                bias_ws[lane * NPOS + gi * 256 + gj] = bv;   // [h][i][j]
            }
        }
    }
    __syncthreads();

    {
        const int row = t >> 3, c8 = (t & 7) * 8;
        *(s16x8*)(h_ws + (size_t)(pos0 + row) * 64 + c8) =
            *(const s16x8*)(smem + row * H_STRIDE + c8);
    }

    const int colbase = wave * 48;
    s16x8 bfrag[3][2];
    #pragma unroll
    for (int nt = 0; nt < 3; ++nt) {
        const int col = colbase + nt * 16 + m;
        const float* wp = w_qkv + (size_t)col * 64;
        #pragma unroll
        for (int kt = 0; kt < 2; ++kt) {
            const float4 w0 = *(const float4*)(wp + kt * 32 + quad * 8);
            const float4 w1 = *(const float4*)(wp + kt * 32 + quad * 8 + 4);
            bfrag[nt][kt] = cvt8(w0, w1);
        }
    }

    s16x8 afrag[4][2];
    #pragma unroll
    for (int mt = 0; mt < 4; ++mt)
        #pragma unroll
        for (int kt = 0; kt < 2; ++kt)
            afrag[mt][kt] = *(const s16x8*)(smem + (mt * 16 + m) * H_STRIDE + kt * 32 + quad * 8);

    f32x4 acc[4][3];
    #pragma unroll
    for (int mt = 0; mt < 4; ++mt)
        #pragma unroll
        for (int nt = 0; nt < 3; ++nt)
            acc[mt][nt] = (f32x4){0.f, 0.f, 0.f, 0.f};

    #pragma unroll
    for (int kt = 0; kt < 2; ++kt)
        #pragma unroll
        for (int mt = 0; mt < 4; ++mt)
            #pragma unroll
            for (int nt = 0; nt < 3; ++nt)
                acc[mt][nt] = __builtin_amdgcn_mfma_f32_16x16x32_bf16(
                    afrag[mt][kt], bfrag[nt][kt], acc[mt][nt], 0, 0, 0);

    __syncthreads();

    #pragma unroll
    for (int mt = 0; mt < 4; ++mt)
        #pragma unroll
        for (int nt = 0; nt < 3; ++nt) {
            const int c = colbase + nt * 16 + m;
            #pragma unroll
            for (int r = 0; r < 4; ++r) {
                const int row = mt * 16 + quad * 4 + r;
                smem[row * Q_STRIDE + c] = bfbits(acc[mt][nt][r]);
            }
        }
    __syncthreads();

    #pragma unroll
    for (int i = 0; i < 6; ++i) {
        const int idx = i * 512 + t;
        const int row = idx / 48, c8 = (idx % 48) * 8;
        *(s16x8*)(qkv_ws + (size_t)(pos0 + row) * EQKV + c8) =
            *(const s16x8*)(smem + row * Q_STRIDE + c8);
    }
}

// ---------------- K2F: fused attention (all 4 heads) + gate + out projection, block = n ----------------
// grid 256, 1024 threads (16 waves). Each block owns one n-slice of qkv (read once) and the
// full 256-position output rows. O accumulates in LDS across h; attn never touches HBM.
__global__ __launch_bounds__(1024, 4) void k2_fused(
    const __hip_bfloat16* __restrict__ qkv_ws, const float* __restrict__ bias_ws,
    const int* __restrict__ mask, const __hip_bfloat16* __restrict__ h_ws,
    const float* __restrict__ w_gate, const float* __restrict__ w_out,
    float* __restrict__ out)
{
    // 156160 B total:
    //   o_x  [256][OXS] bf16  @0       (69632 B)  -> final phase: f32 out staging [256][OFS]
    //   p_s  [128][PS]  bf16  @69632   (67584 B)  -> final phase: h_s [256][H_STRIDE]
    //   vt_s [32][PS]   bf16  @137216  (16896 B)
    //   keep [256]      f32   @154112  (1024 B)
    //   redl [128][2]   f32   @155136  (1024 B)
    __shared__ __align__(16) char smem_raw[156160];
    short* o_x  = (short*)smem_raw;
    short* p_s  = (short*)(smem_raw + 69632);
    short* vt_s = (short*)(smem_raw + 137216);
    float* keep = (float*)(smem_raw + 154112);
    float* redl = (float*)(smem_raw + 155136);

    const int n = blockIdx.x;
    const int t = threadIdx.x;
    const int wave = t >> 6, lane = t & 63;
    const int m = lane & 15, quad = lane >> 4;
    const int mt = wave & 7;     // i-tile of 16 within 128-row i-group
    const int nh = wave >> 3;    // j-half of 128 (QK) / dh-half of 16 (PV)
    const int jcol0 = nh * 128 + m;

    if (t < 256) keep[t] = (mask[n * 256 + t] != 0) ? 1.0f : 0.0f;
    __syncthreads();

    for (int h = 0; h < 4; ++h) {
        // stage V^T for this head: vt_s[dh][j]
        {
            const int j = t >> 2, dh0 = (t & 3) * 8;
            const s16x8 v = *(const s16x8*)(qkv_ws + (size_t)(n * 256 + j) * 384 + 256 + h * 32 + dh0);
            #pragma unroll
            for (int e = 0; e < 8; ++e) vt_s[(dh0 + e) * PS + j] = v[e];
        }
        // K fragments for this wave's j-half
        s16x8 kf[8];
        #pragma unroll
        for (int tt = 0; tt < 8; ++tt)
            kf[tt] = *(const s16x8*)(qkv_ws + (size_t)(n * 256 + (nh * 8 + tt) * 16 + m) * 384 + 128 + h * 32 + quad * 8);
        const float* bias_h = bias_ws + (size_t)h * NPOS;
        s16x8 qf = *(const s16x8*)(qkv_ws + (size_t)(n * 256 + mt * 16 + m) * 384 + h * 32 + quad * 8);

        for (int ig = 0; ig < 2; ++ig) {
            const int i0 = ig * 128;

            // bias loads (coalesced over m; compiler overlaps with the MFMAs below)
            float bb[8][4];
            #pragma unroll
            for (int tt = 0; tt < 8; ++tt)
                #pragma unroll
                for (int r = 0; r < 4; ++r)
                    bb[tt][r] = bias_h[(i0 + mt * 16 + quad * 4 + r) * 256 + jcol0 + tt * 16];

            // S = Q K^T, scale + bias + mask
            f32x4 s[8];
            #pragma unroll
            for (int tt = 0; tt < 8; ++tt) {
                f32x4 z4 = {0.f, 0.f, 0.f, 0.f};
                s[tt] = __builtin_amdgcn_mfma_f32_16x16x32_bf16(qf, kf[tt], z4, 0, 0, 0);
            }
            #pragma unroll
            for (int tt = 0; tt < 8; ++tt) {
                const float kp = keep[jcol0 + tt * 16];
                #pragma unroll
                for (int r = 0; r < 4; ++r) {
                    const float sv = s[tt][r] * SCALE_F + bb[tt][r];
                    s[tt][r] = (kp != 0.f) ? sv : BIG_NEG;
                }
            }

            // exp (no max-sub: |S| bounded by construction), half-row sums, P to LDS
            #pragma unroll
            for (int r = 0; r < 4; ++r) {
                float acc = 0.f;
                #pragma unroll
                for (int tt = 0; tt < 8; ++tt) {
                    const float p = __expf(s[tt][r]);   // masked -> exp(BIG_NEG) = 0
                    s[tt][r] = p;
                    acc += p;
                }
                #pragma unroll
                for (int off = 1; off < 16; off <<= 1) acc += __shfl_xor(acc, off);
                if (m == 0) redl[(mt * 16 + quad * 4 + r) * 2 + nh] = acc;
            }
            #pragma unroll
            for (int tt = 0; tt < 8; ++tt) {
                const int col = jcol0 + tt * 16;
                #pragma unroll
                for (int r = 0; r < 4; ++r)
                    p_s[(mt * 16 + quad * 4 + r) * PS + col] = bfbits(s[tt][r]);
            }

            // prefetch next Q fragment (hides under barrier + PV)
            if (!(h == 3 && ig == 1)) {
                const int hn  = (ig == 0) ? h : h + 1;
                const int i0n = (ig == 0) ? 128 : 0;
                qf = *(const s16x8*)(qkv_ws + (size_t)(n * 256 + i0n + mt * 16 + m) * 384 + hn * 32 + quad * 8);
            }
            __syncthreads();   // p_s, redl, vt_s ready

            // O = P V: 16 waves = 8 i-tiles x 2 dh-halves, dual MFMA chains, write into o_x
            {
                const int dt = nh;
                f32x4 o0 = {0.f, 0.f, 0.f, 0.f};
                f32x4 o1 = {0.f, 0.f, 0.f, 0.f};
                const int arow = mt * 16 + m;
                const int brow = dt * 16 + m;
                #pragma unroll
                for (int kt = 0; kt < 4; ++kt) {
                    const s16x8 ap0 = *(const s16x8*)(p_s + arow * PS + (2 * kt) * 32 + quad * 8);
                    const s16x8 bv0 = *(const s16x8*)(vt_s + brow * PS + (2 * kt) * 32 + quad * 8);
                    o0 = __builtin_amdgcn_mfma_f32_16x16x32_bf16(ap0, bv0, o0, 0, 0, 0);
                    const s16x8 ap1 = *(const s16x8*)(p_s + arow * PS + (2 * kt + 1) * 32 + quad * 8);
                    const s16x8 bv1 = *(const s16x8*)(vt_s + brow * PS + (2 * kt + 1) * 32 + quad * 8);
                    o1 = __builtin_amdgcn_mfma_f32_16x16x32_bf16(ap1, bv1, o1, 0, 0, 0);
                }
                #pragma unroll
                for (int r = 0; r < 4; ++r) {
                    const int row = mt * 16 + quad * 4 + r;
                    const float l = fmaxf(redl[row * 2] + redl[row * 2 + 1], 1e-30f);
                    o_x[(i0 + row) * OXS + h * 32 + dt * 16 + m] =
                        bfbits((o0[r] + o1[r]) * (1.0f / l));
                }
            }
            __syncthreads();   // protect p_s/redl (next ig) and vt_s (next h)
        }
    }

    // ---- final phase: gate = sigmoid(h @ w_gate^T); x = O*gate (in place); out = x @ w_out^T ----
    short* h_s = p_s;   // alias: p_s region free after last PV barrier
    #pragma unroll
    for (int i = 0; i < 2; ++i) {
        const int idx = i * 1024 + t;
        const int row = idx >> 3, c8 = (idx & 7) * 8;
        *(s16x8*)(h_s + row * H_STRIDE + c8) =
            *(const s16x8*)(h_ws + (size_t)(n * 256 + row) * 64 + c8);
    }
    __syncthreads();

    // gate via MFMA + in-place x update (wave rt owns rows rt*16..rt*16+15, all 128 cols)
    {
        const int rt = wave;
        s16x8 ha[2];
        #pragma unroll
        for (int kt = 0; kt < 2; ++kt)
            ha[kt] = *(const s16x8*)(h_s + (rt * 16 + m) * H_STRIDE + kt * 32 + quad * 8);
        #pragma unroll
        for (int ct = 0; ct < 8; ++ct) {
            const float* wp = w_gate + (size_t)(ct * 16 + m) * 64;
            const s16x8 b0 = cvt8(*(const float4*)(wp + quad * 8),
                                  *(const float4*)(wp + quad * 8 + 4));
            const s16x8 b1 = cvt8(*(const float4*)(wp + 32 + quad * 8),
                                  *(const float4*)(wp + 32 + quad * 8 + 4));
            f32x4 g4 = (f32x4){0.f, 0.f, 0.f, 0.f};
            g4 = __builtin_amdgcn_mfma_f32_16x16x32_bf16(ha[0], b0, g4, 0, 0, 0);
            g4 = __builtin_amdgcn_mfma_f32_16x16x32_bf16(ha[1], b1, g4, 0, 0, 0);
            #pragma unroll
            for (int r = 0; r < 4; ++r) {
                const int row = rt * 16 + quad * 4 + r;
                const int col = ct * 16 + m;
                const float gv = 1.0f / (1.0f + __expf(-g4[r]));
                o_x[row * OXS + col] = bfbits(b2f(o_x[row * OXS + col]) * gv);
            }
        }
    }
    __syncthreads();   // x complete across waves

    // out GEMM: each wave: 16 rows x 64 out-cols, K=128
    {
        const int rt = wave;
        s16x8 afrag[4];
        #pragma unroll
        for (int kt = 0; kt < 4; ++kt)
            afrag[kt] = *(const s16x8*)(o_x + (rt * 16 + m) * OXS + kt * 32 + quad * 8);
        f32x4 acc[4];
        #pragma unroll
        for (int nt = 0; nt < 4; ++nt) acc[nt] = (f32x4){0.f, 0.f, 0.f, 0.f};
        #pragma unroll
        for (int nt = 0; nt < 4; ++nt) {
            const float* wp = w_out + (size_t)(nt * 16 + m) * 128;
            #pragma unroll
            for (int kt = 0; kt < 4; ++kt) {
                const s16x8 bf = cvt8(*(const float4*)(wp + kt * 32 + quad * 8),
                                      *(const float4*)(wp + kt * 32 + quad * 8 + 4));
                acc[nt] = __builtin_amdgcn_mfma_f32_16x16x32_bf16(afrag[kt], bf, acc[nt], 0, 0, 0);
            }
        }
        __syncthreads();   // all x reads done -> o_x region reusable as f32 staging
        float* o_f = (float*)o_x;
        #pragma unroll
        for (int nt = 0; nt < 4; ++nt)
            #pragma unroll
            for (int r = 0; r < 4; ++r)
                o_f[(rt * 16 + quad * 4 + r) * OFS + nt * 16 + m] = acc[nt][r];
    }
    __syncthreads();

    // coalesced f32 out stores
    {
        const float* o_f = (const float*)o_x;
        #pragma unroll
        for (int i = 0; i < 4; ++i) {
            const int idx = i * 1024 + t;
            const int row = idx >> 4, c4 = (idx & 15) * 4;
            *(float4*)(out + (size_t)(n * 256 + row) * 64 + c4) =
                *(const float4*)(o_f + row * OFS + c4);
        }
    }
}

extern "C" void kernel_launch(void* const* d_in, const int* in_sizes, int n_in,
                              void* d_out, int out_size, void* d_ws, size_t ws_size,
                              hipStream_t stream) {
    const float* z      = (const float*)d_in[0];
    const int*   mask   = (const int*)d_in[1];
    const float* ln_w   = (const float*)d_in[2];
    const float* ln_b   = (const float*)d_in[3];
    const float* w_qkv  = (const float*)d_in[4];
    const float* w_bias = (const float*)d_in[5];
    const float* w_out  = (const float*)d_in[6];
    const float* w_gate = (const float*)d_in[7];
    float* out = (float*)d_out;

    char* ws = (char*)d_ws;
    __hip_bfloat16* qkv_ws  = (__hip_bfloat16*)(ws);
    float*          bias_ws = (float*)(ws + 50331648);
    __hip_bfloat16* h_ws    = (__hip_bfloat16*)(ws + 51380224);

    k1_ln_proj_mfma<<<1024, 512, 0, stream>>>(z, ln_w, ln_b, w_qkv, w_bias,
                                              qkv_ws, h_ws, bias_ws);
    k2_fused<<<256, 1024, 0, stream>>>(qkv_ws, bias_ws, mask, h_ws,
                                       w_gate, w_out, out);
}